// Round 8
// baseline (2511.050 us; speedup 1.0000x reference)
//
#include <hip/hip_runtime.h>

#define NI 64       // instances
#define CH 64       // channels
#define EPSV 1e-5f
#define CHUNK 1024  // seg stash per block-iteration
#define NBLK 512    // grid for streaming reduction passes
#define PADT 66     // padded LDS table row for k_out

// ---- K1: streaming stats, one point per wave, lane = channel ----
__global__ __launch_bounds__(256) void k_stats_s(const float* __restrict__ f,
                                                 const int* __restrict__ seg,
                                                 float* __restrict__ g_s,
                                                 float* __restrict__ g_s2,
                                                 unsigned* __restrict__ hist,
                                                 float* __restrict__ part,  // [NBLK][8192]
                                                 int mode, int n) {
  __shared__ float ls[NI * CH];    // 16 KB
  __shared__ float ls2[NI * CH];   // 16 KB
  __shared__ unsigned lcnt[NI];
  __shared__ int stash[CHUNK];     // 4 KB
  const int t = threadIdx.x;
  for (int i = t; i < NI * CH; i += 256) { ls[i] = 0.f; ls2[i] = 0.f; }
  if (t < NI) lcnt[t] = 0u;
  __syncthreads();

  const int wave = t >> 6, lane = t & 63;
  for (int base = blockIdx.x * CHUNK; base < n; base += gridDim.x * CHUNK) {
    const int len = min(CHUNK, n - base);
    for (int i = t; i < len; i += 256) stash[i] = seg[base + i];
    __syncthreads();
    int q = wave;
    for (; q + 12 < len; q += 16) {   // 4 points per unrolled wave-iter
      const float v0 = f[(size_t)(base + q) * CH + lane];
      const float v1 = f[(size_t)(base + q + 4) * CH + lane];
      const float v2 = f[(size_t)(base + q + 8) * CH + lane];
      const float v3 = f[(size_t)(base + q + 12) * CH + lane];
      const int i0 = stash[q], i1 = stash[q + 4], i2 = stash[q + 8], i3 = stash[q + 12];
      atomicAdd(&ls[i0 * CH + lane], v0);
      atomicAdd(&ls2[i0 * CH + lane], v0 * v0);
      atomicAdd(&ls[i1 * CH + lane], v1);
      atomicAdd(&ls2[i1 * CH + lane], v1 * v1);
      atomicAdd(&ls[i2 * CH + lane], v2);
      atomicAdd(&ls2[i2 * CH + lane], v2 * v2);
      atomicAdd(&ls[i3 * CH + lane], v3);
      atomicAdd(&ls2[i3 * CH + lane], v3 * v3);
      if (lane == 0) {
        atomicAdd(&lcnt[i0], 1u); atomicAdd(&lcnt[i1], 1u);
        atomicAdd(&lcnt[i2], 1u); atomicAdd(&lcnt[i3], 1u);
      }
    }
    for (; q < len; q += 4) {
      const float v = f[(size_t)(base + q) * CH + lane];
      const int ins = stash[q];
      atomicAdd(&ls[ins * CH + lane], v);
      atomicAdd(&ls2[ins * CH + lane], v * v);
      if (lane == 0) atomicAdd(&lcnt[ins], 1u);
    }
    __syncthreads();   // protect stash before next refill
  }

  if (mode) {
    float* myp = part + (size_t)blockIdx.x * (2 * NI * CH);
    for (int i = t; i < NI * CH; i += 256) {
      myp[i] = ls[i];
      myp[i + NI * CH] = ls2[i];
    }
  } else {
    for (int i = t; i < NI * CH; i += 256) {
      atomicAdd(&g_s[i], ls[i]);
      atomicAdd(&g_s2[i], ls2[i]);
    }
  }
  if (t < NI) atomicAdd(&hist[t], lcnt[t]);
}

// ---- generic partial reducer: dst[e] = sum_b part[b*len+e] ----
__global__ __launch_bounds__(256) void k_reduce(const float* __restrict__ part,
                                                float* __restrict__ dst,
                                                int nblk, int len) {
  const int e = blockIdx.x * 256 + threadIdx.x;
  if (e >= len) return;
  float acc = 0.f;
  for (int b = 0; b < nblk; ++b) acc += part[(size_t)b * len + e];
  dst[e] = acc;
}

// ---- K2: inv = rsqrt(var+eps), mi = mu*inv ----
__global__ __launch_bounds__(256) void k_musig(const float* __restrict__ g_s,
                                               const float* __restrict__ g_s2,
                                               const unsigned* __restrict__ cnt,
                                               float* __restrict__ g_inv,
                                               float* __restrict__ g_mi) {
  const int i = blockIdx.x * 256 + threadIdx.x;  // grid 16 -> 4096
  const float c = fmaxf((float)cnt[i >> 6], 1.f);
  const float mu = g_s[i] / c;
  const float var = fmaxf(g_s2[i] / c - mu * mu, 0.f);
  const float inv = rsqrtf(var + EPSV);
  g_inv[i] = inv;
  g_mi[i] = mu * inv;
}

// ---- K3: streaming rsum of relu(fma(f,inv,-mi)), lane = channel ----
__global__ __launch_bounds__(256) void k_rsum_s(const float* __restrict__ f,
                                                const int* __restrict__ seg,
                                                const float* __restrict__ g_inv,
                                                const float* __restrict__ g_mi,
                                                float* __restrict__ g_rsum,
                                                float* __restrict__ part,  // [NBLK][4096]
                                                int mode, int n) {
  __shared__ float tinv[NI * CH];  // 16 KB
  __shared__ float tmi[NI * CH];   // 16 KB
  __shared__ float lr[NI * CH];    // 16 KB
  __shared__ int stash[CHUNK];     // 4 KB
  const int t = threadIdx.x;
  for (int i = t; i < NI * CH; i += 256) {
    tinv[i] = g_inv[i];
    tmi[i] = g_mi[i];
    lr[i] = 0.f;
  }
  __syncthreads();

  const int wave = t >> 6, lane = t & 63;
  for (int base = blockIdx.x * CHUNK; base < n; base += gridDim.x * CHUNK) {
    const int len = min(CHUNK, n - base);
    for (int i = t; i < len; i += 256) stash[i] = seg[base + i];
    __syncthreads();
    int q = wave;
    for (; q + 12 < len; q += 16) {
      const float v0 = f[(size_t)(base + q) * CH + lane];
      const float v1 = f[(size_t)(base + q + 4) * CH + lane];
      const float v2 = f[(size_t)(base + q + 8) * CH + lane];
      const float v3 = f[(size_t)(base + q + 12) * CH + lane];
      const int i0 = stash[q], i1 = stash[q + 4], i2 = stash[q + 8], i3 = stash[q + 12];
      const float x0 = fmaxf(fmaf(v0, tinv[i0 * CH + lane], -tmi[i0 * CH + lane]), 0.f);
      const float x1 = fmaxf(fmaf(v1, tinv[i1 * CH + lane], -tmi[i1 * CH + lane]), 0.f);
      const float x2 = fmaxf(fmaf(v2, tinv[i2 * CH + lane], -tmi[i2 * CH + lane]), 0.f);
      const float x3 = fmaxf(fmaf(v3, tinv[i3 * CH + lane], -tmi[i3 * CH + lane]), 0.f);
      atomicAdd(&lr[i0 * CH + lane], x0);
      atomicAdd(&lr[i1 * CH + lane], x1);
      atomicAdd(&lr[i2 * CH + lane], x2);
      atomicAdd(&lr[i3 * CH + lane], x3);
    }
    for (; q < len; q += 4) {
      const float v = f[(size_t)(base + q) * CH + lane];
      const int ins = stash[q];
      const float x = fmaxf(fmaf(v, tinv[ins * CH + lane], -tmi[ins * CH + lane]), 0.f);
      atomicAdd(&lr[ins * CH + lane], x);
    }
    __syncthreads();
  }

  if (mode) {
    float* myp = part + (size_t)blockIdx.x * (NI * CH);
    for (int i = t; i < NI * CH; i += 256) myp[i] = lr[i];
  } else {
    for (int i = t; i < NI * CH; i += 256) atomicAdd(&g_rsum[i], lr[i]);
  }
}

// ---- K4: m = rsum/cnt -> conv3 -> sigmoid -> A = inv*w, B = mi*w ----
__global__ __launch_bounds__(256) void k_eca(const float* __restrict__ g_rsum,
                                             const unsigned* __restrict__ cnt,
                                             const float* __restrict__ ew,
                                             const float* __restrict__ g_inv,
                                             const float* __restrict__ g_mi,
                                             float* __restrict__ g_A,
                                             float* __restrict__ g_B) {
  __shared__ float m[NI * CH];
  const int t = threadIdx.x;
  for (int i = t; i < NI * CH; i += 256)
    m[i] = g_rsum[i] / fmaxf((float)cnt[i >> 6], 1.f);
  __syncthreads();
  const float e0 = ew[0], e1 = ew[1], e2 = ew[2];
  for (int i = t; i < NI * CH; i += 256) {
    const int c = i & 63;
    const float a = c ? m[i - 1] : 0.f;
    const float b = m[i];
    const float d = (c < 63) ? m[i + 1] : 0.f;
    const float conv = e0 * a + e1 * b + e2 * d;
    const float w = 1.f / (1.f + expf(-conv));
    g_A[i] = g_inv[i] * w;
    g_B[i] = g_mi[i] * w;
  }
}

// ---- K5: out = relu(fma(f, A, -B)), contiguous streaming (proven @6.2 TB/s) ----
__global__ __launch_bounds__(256) void k_out(const float* __restrict__ f,
                                             const int* __restrict__ seg,
                                             const float* __restrict__ g_A,
                                             const float* __restrict__ g_B,
                                             float* __restrict__ out, int n) {
  __shared__ float tA[NI * PADT];
  __shared__ float tB[NI * PADT];
  const int t = threadIdx.x;
  for (int i = t; i < NI * CH; i += 256) {
    const int a = (i >> 6) * PADT + (i & 63);
    tA[a] = g_A[i];
    tB[a] = g_B[i];
  }
  __syncthreads();
  const int sub = t & 15, c0 = sub << 2, pib = t >> 4;
  const int pstride = gridDim.x << 4;
  for (int p = (blockIdx.x << 4) + pib; p < n; p += pstride) {
    const float4 v = *reinterpret_cast<const float4*>(f + (size_t)p * CH + c0);
    const int tb = seg[p] * PADT + c0;
    const float4 a = *reinterpret_cast<const float4*>(tA + tb);
    const float4 b = *reinterpret_cast<const float4*>(tB + tb);
    float4 o;
    o.x = fmaxf(fmaf(v.x, a.x, -b.x), 0.f);
    o.y = fmaxf(fmaf(v.y, a.y, -b.y), 0.f);
    o.z = fmaxf(fmaf(v.z, a.z, -b.z), 0.f);
    o.w = fmaxf(fmaf(v.w, a.w, -b.w), 0.f);
    *reinterpret_cast<float4*>(out + (size_t)p * CH + c0) = o;
  }
}

// ================= launch =================
extern "C" void kernel_launch(void* const* d_in, const int* in_sizes, int n_in,
                              void* d_out, int out_size, void* d_ws, size_t ws_size,
                              hipStream_t stream) {
  const float* f   = (const float*)d_in[0];
  const int*   seg = (const int*)d_in[1];
  const float* ew  = (const float*)d_in[2];
  float* out = (float*)d_out;
  const int n = in_sizes[1];

  // ws layout (float offsets)
  float* ws      = (float*)d_ws;
  float* g_s     = ws;                       // 4096
  float* g_s2    = ws + 4096;                // 4096 (contiguous with g_s for combined reduce)
  float* g_rsum  = ws + 8192;                // 4096
  unsigned* hist = (unsigned*)(ws + 12288);  // 64 (= counts)
  float* g_inv   = ws + 12352;               // 4096
  float* g_mi    = ws + 16448;               // 4096
  float* g_A     = ws + 20544;               // 4096
  float* g_B     = ws + 24640;               // 4096
  float* part1   = ws + 28736;               // NBLK * 8192
  float* part3   = part1 + (size_t)NBLK * 8192;  // NBLK * 4096
  const size_t need = (28736 + (size_t)NBLK * 8192 + (size_t)NBLK * 4096) * 4;
  const int mode = (ws_size >= need) ? 1 : 0;  // 1: partials, 0: atomic flush

  // zero accumulators (g_s, g_s2, g_rsum) + hist
  (void)hipMemsetAsync(d_ws, 0, (12288 + 64) * sizeof(float), stream);

  k_stats_s<<<NBLK, 256, 0, stream>>>(f, seg, g_s, g_s2, hist, part1, mode, n);
  if (mode) k_reduce<<<32, 256, 0, stream>>>(part1, g_s /* covers g_s+g_s2 */, NBLK, 8192);
  k_musig<<<16, 256, 0, stream>>>(g_s, g_s2, hist, g_inv, g_mi);
  k_rsum_s<<<NBLK, 256, 0, stream>>>(f, seg, g_inv, g_mi, g_rsum, part3, mode, n);
  if (mode) k_reduce<<<16, 256, 0, stream>>>(part3, g_rsum, NBLK, 4096);
  k_eca<<<1, 256, 0, stream>>>(g_rsum, hist, ew, g_inv, g_mi, g_A, g_B);
  k_out<<<2048, 256, 0, stream>>>(f, seg, g_A, g_B, out, n);
}

// Round 9
// 1538.603 us; speedup vs baseline: 1.6320x; 1.6320x over previous
//
#include <hip/hip_runtime.h>

#define NI 64
#define CH 64
#define EPSV 1e-5f
#define GRID_M 2048     // blocks for mfma streaming passes
#define CHUNKP 64       // points per chunk (2 K-tiles of 32)
#define ROWB 144        // LDS bytes per channel row: 64*2 + 16 pad (16B-aligned)
#define PADT 66         // padded LDS table row for k_out

typedef short bf16x8 __attribute__((ext_vector_type(8)));
typedef float f32x4 __attribute__((ext_vector_type(4)));

__device__ __forceinline__ unsigned short rne_bf16(float x) {
  unsigned u = __float_as_uint(x);
  u += 0x7FFFu + ((u >> 16) & 1u);
  return (unsigned short)(u >> 16);
}

// ---- K0: per-instance counts (proven) ----
__global__ __launch_bounds__(256) void k_hist(const int* __restrict__ seg,
                                              unsigned* __restrict__ hist, int n) {
  __shared__ unsigned h[NI];
  const int t = threadIdx.x;
  if (t < NI) h[t] = 0u;
  __syncthreads();
  const int stride = gridDim.x * 256;
  const int n4 = n >> 2;
  for (int i = blockIdx.x * 256 + t; i < n4; i += stride) {
    const int4 s = reinterpret_cast<const int4*>(seg)[i];
    atomicAdd(&h[s.x], 1u); atomicAdd(&h[s.y], 1u);
    atomicAdd(&h[s.z], 1u); atomicAdd(&h[s.w], 1u);
  }
  if (blockIdx.x == 0)
    for (int i = (n4 << 2) + t; i < n; i += 256) atomicAdd(&h[seg[i]], 1u);
  __syncthreads();
  if (t < NI) atomicAdd(&hist[t], h[t]);
}

// ---- K1: streaming stats via one-hot MFMA segment-sum ----
// grid GRID_M x 256 (4 waves). Chunk = 64 points. Wave w owns instance rows
// [16w,16w+16) x all 64 channels (4 ch-tiles), acc in f32x4 tiles.
__global__ __launch_bounds__(256) void k_mstats(const float* __restrict__ f,
                                                const int* __restrict__ seg,
                                                float* __restrict__ part,   // [GRID_M][8192]
                                                float* __restrict__ g_s,
                                                float* __restrict__ g_s2,
                                                int mode, int n, int nchunk) {
  __shared__ __align__(16) int stash[CHUNKP];
  __shared__ __align__(16) unsigned char lds[2 * CH * ROWB];  // x | x^2, bf16 [ch][pt]
  unsigned char* ldsx = lds;
  unsigned char* ldsq = lds + CH * ROWB;
  const int t = threadIdx.x;
  const int lane = t & 63, wv = t >> 6;
  const int ptpair = t >> 3;          // 0..31 (points 2*ptpair, 2*ptpair+1)
  const int ch8 = (t & 7) * 8;        // 8 channels per thread
  const int i_base = wv * 16;
  const int mrow = lane & 15;
  const int kgrp = lane >> 4;         // 0..3

  f32x4 accs[4] = {{0.f,0.f,0.f,0.f},{0.f,0.f,0.f,0.f},{0.f,0.f,0.f,0.f},{0.f,0.f,0.f,0.f}};
  f32x4 accq[4] = {{0.f,0.f,0.f,0.f},{0.f,0.f,0.f,0.f},{0.f,0.f,0.f,0.f},{0.f,0.f,0.f,0.f}};

  for (int ck = blockIdx.x; ck < nchunk; ck += GRID_M) {
    const int base = ck * CHUNKP;
    if (t < CHUNKP) stash[t] = (base + t < n) ? seg[base + t] : -1;
    __syncthreads();
    // ---- stage: rows 2*ptpair(+1), channels ch8..ch8+8, bf16 transposed ----
    {
      const int r0 = base + 2 * ptpair;
      float va[8], vb[8];
      if (r0 < n) {
        *reinterpret_cast<float4*>(&va[0]) = *reinterpret_cast<const float4*>(f + (size_t)r0 * CH + ch8);
        *reinterpret_cast<float4*>(&va[4]) = *reinterpret_cast<const float4*>(f + (size_t)r0 * CH + ch8 + 4);
      } else {
#pragma unroll
        for (int j = 0; j < 8; ++j) va[j] = 0.f;
      }
      if (r0 + 1 < n) {
        *reinterpret_cast<float4*>(&vb[0]) = *reinterpret_cast<const float4*>(f + (size_t)(r0 + 1) * CH + ch8);
        *reinterpret_cast<float4*>(&vb[4]) = *reinterpret_cast<const float4*>(f + (size_t)(r0 + 1) * CH + ch8 + 4);
      } else {
#pragma unroll
        for (int j = 0; j < 8; ++j) vb[j] = 0.f;
      }
#pragma unroll
      for (int j = 0; j < 8; ++j) {
        const int c = ch8 + j;
        const unsigned px = (unsigned)rne_bf16(va[j]) | ((unsigned)rne_bf16(vb[j]) << 16);
        const unsigned pq = (unsigned)rne_bf16(va[j] * va[j]) | ((unsigned)rne_bf16(vb[j] * vb[j]) << 16);
        *reinterpret_cast<unsigned*>(ldsx + c * ROWB + ptpair * 4) = px;
        *reinterpret_cast<unsigned*>(ldsq + c * ROWB + ptpair * 4) = pq;
      }
    }
    __syncthreads();
    // ---- mfma: 2 K-tiles of 32 ----
#pragma unroll
    for (int kt = 0; kt < 2; ++kt) {
      const int k0 = kt * 32 + kgrp * 8;
      const int4 sA = *reinterpret_cast<const int4*>(&stash[k0]);
      const int4 sB = *reinterpret_cast<const int4*>(&stash[k0 + 4]);
      const int myi = i_base + mrow;
      bf16x8 af;
      af[0] = (sA.x == myi) ? (short)0x3F80 : (short)0;
      af[1] = (sA.y == myi) ? (short)0x3F80 : (short)0;
      af[2] = (sA.z == myi) ? (short)0x3F80 : (short)0;
      af[3] = (sA.w == myi) ? (short)0x3F80 : (short)0;
      af[4] = (sB.x == myi) ? (short)0x3F80 : (short)0;
      af[5] = (sB.y == myi) ? (short)0x3F80 : (short)0;
      af[6] = (sB.z == myi) ? (short)0x3F80 : (short)0;
      af[7] = (sB.w == myi) ? (short)0x3F80 : (short)0;
#pragma unroll
      for (int tc = 0; tc < 4; ++tc) {
        const int c = tc * 16 + mrow;
        const bf16x8 bx = *reinterpret_cast<const bf16x8*>(ldsx + c * ROWB + k0 * 2);
        const bf16x8 bq = *reinterpret_cast<const bf16x8*>(ldsq + c * ROWB + k0 * 2);
        accs[tc] = __builtin_amdgcn_mfma_f32_16x16x32_bf16(af, bx, accs[tc], 0, 0, 0);
        accq[tc] = __builtin_amdgcn_mfma_f32_16x16x32_bf16(af, bq, accq[tc], 0, 0, 0);
      }
    }
    __syncthreads();  // protect stash+stage before next chunk
  }
  // ---- flush ----
  if (mode) {
    float* myp = part + (size_t)blockIdx.x * (2 * NI * CH);
#pragma unroll
    for (int tc = 0; tc < 4; ++tc)
#pragma unroll
      for (int r = 0; r < 4; ++r) {
        const int i = i_base + kgrp * 4 + r;
        const int c = tc * 16 + mrow;
        myp[i * CH + c] = accs[tc][r];
        myp[NI * CH + i * CH + c] = accq[tc][r];
      }
  } else {
#pragma unroll
    for (int tc = 0; tc < 4; ++tc)
#pragma unroll
      for (int r = 0; r < 4; ++r) {
        const int i = i_base + kgrp * 4 + r;
        const int c = tc * 16 + mrow;
        atomicAdd(&g_s[i * CH + c], accs[tc][r]);
        atomicAdd(&g_s2[i * CH + c], accq[tc][r]);
      }
  }
}

// ---- generic partial reducer (proven) ----
__global__ __launch_bounds__(256) void k_reduce(const float* __restrict__ part,
                                                float* __restrict__ dst,
                                                int nblk, int len) {
  const int e = blockIdx.x * 256 + threadIdx.x;
  if (e >= len) return;
  float acc = 0.f;
  for (int b = 0; b < nblk; ++b) acc += part[(size_t)b * len + e];
  dst[e] = acc;
}

// ---- K2: inv = rsqrt(var+eps), mi = mu*inv (proven) ----
__global__ __launch_bounds__(256) void k_musig(const float* __restrict__ g_s,
                                               const float* __restrict__ g_s2,
                                               const unsigned* __restrict__ cnt,
                                               float* __restrict__ g_inv,
                                               float* __restrict__ g_mi) {
  const int i = blockIdx.x * 256 + threadIdx.x;
  const float c = fmaxf((float)cnt[i >> 6], 1.f);
  const float mu = g_s[i] / c;
  const float var = fmaxf(g_s2[i] / c - mu * mu, 0.f);
  const float inv = rsqrtf(var + EPSV);
  g_inv[i] = inv;
  g_mi[i] = mu * inv;
}

// ---- K3: streaming relu-segsum via one-hot MFMA ----
__global__ __launch_bounds__(256) void k_mrsum(const float* __restrict__ f,
                                               const int* __restrict__ seg,
                                               const float* __restrict__ g_inv,
                                               const float* __restrict__ g_mi,
                                               float* __restrict__ part,   // [GRID_M][4096]
                                               float* __restrict__ g_rsum,
                                               int mode, int n, int nchunk) {
  __shared__ __align__(16) int stash[CHUNKP];
  __shared__ __align__(16) unsigned char ldsr[CH * ROWB];   // relu(xn) bf16 [ch][pt]
  const int t = threadIdx.x;
  const int lane = t & 63, wv = t >> 6;
  const int ptpair = t >> 3;
  const int ch8 = (t & 7) * 8;
  const int i_base = wv * 16;
  const int mrow = lane & 15;
  const int kgrp = lane >> 4;
  const float4* giv = reinterpret_cast<const float4*>(g_inv);
  const float4* gmi = reinterpret_cast<const float4*>(g_mi);
  const int cq = ch8 >> 2;

  f32x4 acc[4] = {{0.f,0.f,0.f,0.f},{0.f,0.f,0.f,0.f},{0.f,0.f,0.f,0.f},{0.f,0.f,0.f,0.f}};

  for (int ck = blockIdx.x; ck < nchunk; ck += GRID_M) {
    const int base = ck * CHUNKP;
    if (t < CHUNKP) stash[t] = (base + t < n) ? seg[base + t] : -1;
    __syncthreads();
    {
      const int r0 = base + 2 * ptpair;
      const float m0 = (r0 < n) ? 1.f : 0.f;
      const float m1 = (r0 + 1 < n) ? 1.f : 0.f;
      float va[8], vb[8];
      if (r0 < n) {
        *reinterpret_cast<float4*>(&va[0]) = *reinterpret_cast<const float4*>(f + (size_t)r0 * CH + ch8);
        *reinterpret_cast<float4*>(&va[4]) = *reinterpret_cast<const float4*>(f + (size_t)r0 * CH + ch8 + 4);
      } else {
#pragma unroll
        for (int j = 0; j < 8; ++j) va[j] = 0.f;
      }
      if (r0 + 1 < n) {
        *reinterpret_cast<float4*>(&vb[0]) = *reinterpret_cast<const float4*>(f + (size_t)(r0 + 1) * CH + ch8);
        *reinterpret_cast<float4*>(&vb[4]) = *reinterpret_cast<const float4*>(f + (size_t)(r0 + 1) * CH + ch8 + 4);
      } else {
#pragma unroll
        for (int j = 0; j < 8; ++j) vb[j] = 0.f;
      }
      int ins0 = stash[2 * ptpair];     if (ins0 < 0) ins0 = 0;
      int ins1 = stash[2 * ptpair + 1]; if (ins1 < 0) ins1 = 0;
      float iva[8], mia[8], ivb[8], mib[8];
      *reinterpret_cast<float4*>(&iva[0]) = giv[ins0 * 16 + cq];
      *reinterpret_cast<float4*>(&iva[4]) = giv[ins0 * 16 + cq + 1];
      *reinterpret_cast<float4*>(&mia[0]) = gmi[ins0 * 16 + cq];
      *reinterpret_cast<float4*>(&mia[4]) = gmi[ins0 * 16 + cq + 1];
      *reinterpret_cast<float4*>(&ivb[0]) = giv[ins1 * 16 + cq];
      *reinterpret_cast<float4*>(&ivb[4]) = giv[ins1 * 16 + cq + 1];
      *reinterpret_cast<float4*>(&mib[0]) = gmi[ins1 * 16 + cq];
      *reinterpret_cast<float4*>(&mib[4]) = gmi[ins1 * 16 + cq + 1];
#pragma unroll
      for (int j = 0; j < 8; ++j) {
        const int c = ch8 + j;
        const float x0 = fmaxf(fmaf(va[j], iva[j], -mia[j]), 0.f) * m0;
        const float x1 = fmaxf(fmaf(vb[j], ivb[j], -mib[j]), 0.f) * m1;
        *reinterpret_cast<unsigned*>(ldsr + c * ROWB + ptpair * 4) =
            (unsigned)rne_bf16(x0) | ((unsigned)rne_bf16(x1) << 16);
      }
    }
    __syncthreads();
#pragma unroll
    for (int kt = 0; kt < 2; ++kt) {
      const int k0 = kt * 32 + kgrp * 8;
      const int4 sA = *reinterpret_cast<const int4*>(&stash[k0]);
      const int4 sB = *reinterpret_cast<const int4*>(&stash[k0 + 4]);
      const int myi = i_base + mrow;
      bf16x8 af;
      af[0] = (sA.x == myi) ? (short)0x3F80 : (short)0;
      af[1] = (sA.y == myi) ? (short)0x3F80 : (short)0;
      af[2] = (sA.z == myi) ? (short)0x3F80 : (short)0;
      af[3] = (sA.w == myi) ? (short)0x3F80 : (short)0;
      af[4] = (sB.x == myi) ? (short)0x3F80 : (short)0;
      af[5] = (sB.y == myi) ? (short)0x3F80 : (short)0;
      af[6] = (sB.z == myi) ? (short)0x3F80 : (short)0;
      af[7] = (sB.w == myi) ? (short)0x3F80 : (short)0;
#pragma unroll
      for (int tc = 0; tc < 4; ++tc) {
        const int c = tc * 16 + mrow;
        const bf16x8 br = *reinterpret_cast<const bf16x8*>(ldsr + c * ROWB + k0 * 2);
        acc[tc] = __builtin_amdgcn_mfma_f32_16x16x32_bf16(af, br, acc[tc], 0, 0, 0);
      }
    }
    __syncthreads();
  }
  if (mode) {
    float* myp = part + (size_t)blockIdx.x * (NI * CH);
#pragma unroll
    for (int tc = 0; tc < 4; ++tc)
#pragma unroll
      for (int r = 0; r < 4; ++r)
        myp[(i_base + kgrp * 4 + r) * CH + tc * 16 + mrow] = acc[tc][r];
  } else {
#pragma unroll
    for (int tc = 0; tc < 4; ++tc)
#pragma unroll
      for (int r = 0; r < 4; ++r)
        atomicAdd(&g_rsum[(i_base + kgrp * 4 + r) * CH + tc * 16 + mrow], acc[tc][r]);
  }
}

// ---- K4: m = rsum/cnt -> conv3 -> sigmoid -> A,B (proven) ----
__global__ __launch_bounds__(256) void k_eca(const float* __restrict__ g_rsum,
                                             const unsigned* __restrict__ cnt,
                                             const float* __restrict__ ew,
                                             const float* __restrict__ g_inv,
                                             const float* __restrict__ g_mi,
                                             float* __restrict__ g_A,
                                             float* __restrict__ g_B) {
  __shared__ float m[NI * CH];
  const int t = threadIdx.x;
  for (int i = t; i < NI * CH; i += 256)
    m[i] = g_rsum[i] / fmaxf((float)cnt[i >> 6], 1.f);
  __syncthreads();
  const float e0 = ew[0], e1 = ew[1], e2 = ew[2];
  for (int i = t; i < NI * CH; i += 256) {
    const int c = i & 63;
    const float a = c ? m[i - 1] : 0.f;
    const float b = m[i];
    const float d = (c < 63) ? m[i + 1] : 0.f;
    const float conv = e0 * a + e1 * b + e2 * d;
    const float w = 1.f / (1.f + expf(-conv));
    g_A[i] = g_inv[i] * w;
    g_B[i] = g_mi[i] * w;
  }
}

// ---- K5: out = relu(fma(f, A, -B)) streaming (proven @~6.2 TB/s) ----
__global__ __launch_bounds__(256) void k_out(const float* __restrict__ f,
                                             const int* __restrict__ seg,
                                             const float* __restrict__ g_A,
                                             const float* __restrict__ g_B,
                                             float* __restrict__ out, int n) {
  __shared__ float tA[NI * PADT];
  __shared__ float tB[NI * PADT];
  const int t = threadIdx.x;
  for (int i = t; i < NI * CH; i += 256) {
    const int a = (i >> 6) * PADT + (i & 63);
    tA[a] = g_A[i];
    tB[a] = g_B[i];
  }
  __syncthreads();
  const int sub = t & 15, c0 = sub << 2, pib = t >> 4;
  const int pstride = gridDim.x << 4;
  for (int p = (blockIdx.x << 4) + pib; p < n; p += pstride) {
    const float4 v = *reinterpret_cast<const float4*>(f + (size_t)p * CH + c0);
    const int tb = seg[p] * PADT + c0;
    const float4 a = *reinterpret_cast<const float4*>(tA + tb);
    const float4 b = *reinterpret_cast<const float4*>(tB + tb);
    float4 o;
    o.x = fmaxf(fmaf(v.x, a.x, -b.x), 0.f);
    o.y = fmaxf(fmaf(v.y, a.y, -b.y), 0.f);
    o.z = fmaxf(fmaf(v.z, a.z, -b.z), 0.f);
    o.w = fmaxf(fmaf(v.w, a.w, -b.w), 0.f);
    *reinterpret_cast<float4*>(out + (size_t)p * CH + c0) = o;
  }
}

// ================= launch =================
extern "C" void kernel_launch(void* const* d_in, const int* in_sizes, int n_in,
                              void* d_out, int out_size, void* d_ws, size_t ws_size,
                              hipStream_t stream) {
  const float* f   = (const float*)d_in[0];
  const int*   seg = (const int*)d_in[1];
  const float* ew  = (const float*)d_in[2];
  float* out = (float*)d_out;
  const int n = in_sizes[1];
  const int nchunk = (n + CHUNKP - 1) / CHUNKP;

  // ws layout (float offsets)
  float* ws      = (float*)d_ws;
  float* g_s     = ws;                       // 4096
  float* g_s2    = ws + 4096;                // 4096 (contiguous with g_s for combined reduce)
  float* g_rsum  = ws + 8192;                // 4096
  unsigned* hist = (unsigned*)(ws + 12288);  // 64
  float* g_inv   = ws + 12352;               // 4096
  float* g_mi    = ws + 16448;               // 4096
  float* g_A     = ws + 20544;               // 4096
  float* g_B     = ws + 24640;               // 4096
  float* part1   = ws + 28736;               // GRID_M * 8192
  float* part3   = part1 + (size_t)GRID_M * 8192;  // GRID_M * 4096
  const size_t need = (28736 + (size_t)GRID_M * 8192 + (size_t)GRID_M * 4096) * 4;
  const int mode = (ws_size >= need) ? 1 : 0;

  // zero g_s, g_s2, g_rsum, hist (reduce overwrites in mode 1; atomics need zeros in mode 0)
  (void)hipMemsetAsync(d_ws, 0, 12352 * sizeof(float), stream);

  k_hist<<<256, 256, 0, stream>>>(seg, hist, n);
  k_mstats<<<GRID_M, 256, 0, stream>>>(f, seg, part1, g_s, g_s2, mode, n, nchunk);
  if (mode) k_reduce<<<32, 256, 0, stream>>>(part1, g_s /* + g_s2 */, GRID_M, 8192);
  k_musig<<<16, 256, 0, stream>>>(g_s, g_s2, hist, g_inv, g_mi);
  k_mrsum<<<GRID_M, 256, 0, stream>>>(f, seg, g_inv, g_mi, part3, g_rsum, mode, n, nchunk);
  if (mode) k_reduce<<<16, 256, 0, stream>>>(part3, g_rsum, GRID_M, 4096);
  k_eca<<<1, 256, 0, stream>>>(g_rsum, hist, ew, g_inv, g_mi, g_A, g_B);
  k_out<<<2048, 256, 0, stream>>>(f, seg, g_A, g_B, out, n);
}

// Round 10
// 497.481 us; speedup vs baseline: 5.0475x; 3.0928x over previous
//
#include <hip/hip_runtime.h>

#define NI 64
#define CH 64
#define EPSV 1e-5f
#define GRID_M 2048     // blocks for mfma streaming passes
#define CHUNKP 64       // points per chunk (2 K-tiles of 32)
#define ROWB 144        // LDS bytes per channel row: 64*2 + 16 pad (16B-aligned)
#define PADT 66         // padded LDS table row for k_out
#define NSL 64          // reducer slices over the partial-block dim

typedef short bf16x8 __attribute__((ext_vector_type(8)));
typedef float f32x4 __attribute__((ext_vector_type(4)));

__device__ __forceinline__ unsigned short rne_bf16(float x) {
  unsigned u = __float_as_uint(x);
  u += 0x7FFFu + ((u >> 16) & 1u);
  return (unsigned short)(u >> 16);
}

// ---- K0: per-instance counts (proven) ----
__global__ __launch_bounds__(256) void k_hist(const int* __restrict__ seg,
                                              unsigned* __restrict__ hist, int n) {
  __shared__ unsigned h[NI];
  const int t = threadIdx.x;
  if (t < NI) h[t] = 0u;
  __syncthreads();
  const int stride = gridDim.x * 256;
  const int n4 = n >> 2;
  for (int i = blockIdx.x * 256 + t; i < n4; i += stride) {
    const int4 s = reinterpret_cast<const int4*>(seg)[i];
    atomicAdd(&h[s.x], 1u); atomicAdd(&h[s.y], 1u);
    atomicAdd(&h[s.z], 1u); atomicAdd(&h[s.w], 1u);
  }
  if (blockIdx.x == 0)
    for (int i = (n4 << 2) + t; i < n; i += 256) atomicAdd(&h[seg[i]], 1u);
  __syncthreads();
  if (t < NI) atomicAdd(&hist[t], h[t]);
}

// ---- K1: streaming stats via one-hot MFMA segment-sum (proven r9) ----
__global__ __launch_bounds__(256) void k_mstats(const float* __restrict__ f,
                                                const int* __restrict__ seg,
                                                float* __restrict__ part,   // [GRID_M][8192]
                                                float* __restrict__ g_s,
                                                float* __restrict__ g_s2,
                                                int mode, int n, int nchunk) {
  __shared__ __align__(16) int stash[CHUNKP];
  __shared__ __align__(16) unsigned char lds[2 * CH * ROWB];  // x | x^2, bf16 [ch][pt]
  unsigned char* ldsx = lds;
  unsigned char* ldsq = lds + CH * ROWB;
  const int t = threadIdx.x;
  const int lane = t & 63, wv = t >> 6;
  const int ptpair = t >> 3;          // 0..31 (points 2*ptpair, 2*ptpair+1)
  const int ch8 = (t & 7) * 8;        // 8 channels per thread
  const int i_base = wv * 16;
  const int mrow = lane & 15;
  const int kgrp = lane >> 4;         // 0..3

  f32x4 accs[4] = {{0.f,0.f,0.f,0.f},{0.f,0.f,0.f,0.f},{0.f,0.f,0.f,0.f},{0.f,0.f,0.f,0.f}};
  f32x4 accq[4] = {{0.f,0.f,0.f,0.f},{0.f,0.f,0.f,0.f},{0.f,0.f,0.f,0.f},{0.f,0.f,0.f,0.f}};

  for (int ck = blockIdx.x; ck < nchunk; ck += GRID_M) {
    const int base = ck * CHUNKP;
    if (t < CHUNKP) stash[t] = (base + t < n) ? seg[base + t] : -1;
    __syncthreads();
    {
      const int r0 = base + 2 * ptpair;
      float va[8], vb[8];
      if (r0 < n) {
        *reinterpret_cast<float4*>(&va[0]) = *reinterpret_cast<const float4*>(f + (size_t)r0 * CH + ch8);
        *reinterpret_cast<float4*>(&va[4]) = *reinterpret_cast<const float4*>(f + (size_t)r0 * CH + ch8 + 4);
      } else {
#pragma unroll
        for (int j = 0; j < 8; ++j) va[j] = 0.f;
      }
      if (r0 + 1 < n) {
        *reinterpret_cast<float4*>(&vb[0]) = *reinterpret_cast<const float4*>(f + (size_t)(r0 + 1) * CH + ch8);
        *reinterpret_cast<float4*>(&vb[4]) = *reinterpret_cast<const float4*>(f + (size_t)(r0 + 1) * CH + ch8 + 4);
      } else {
#pragma unroll
        for (int j = 0; j < 8; ++j) vb[j] = 0.f;
      }
#pragma unroll
      for (int j = 0; j < 8; ++j) {
        const int c = ch8 + j;
        const unsigned px = (unsigned)rne_bf16(va[j]) | ((unsigned)rne_bf16(vb[j]) << 16);
        const unsigned pq = (unsigned)rne_bf16(va[j] * va[j]) | ((unsigned)rne_bf16(vb[j] * vb[j]) << 16);
        *reinterpret_cast<unsigned*>(ldsx + c * ROWB + ptpair * 4) = px;
        *reinterpret_cast<unsigned*>(ldsq + c * ROWB + ptpair * 4) = pq;
      }
    }
    __syncthreads();
#pragma unroll
    for (int kt = 0; kt < 2; ++kt) {
      const int k0 = kt * 32 + kgrp * 8;
      const int4 sA = *reinterpret_cast<const int4*>(&stash[k0]);
      const int4 sB = *reinterpret_cast<const int4*>(&stash[k0 + 4]);
      const int myi = i_base + mrow;
      bf16x8 af;
      af[0] = (sA.x == myi) ? (short)0x3F80 : (short)0;
      af[1] = (sA.y == myi) ? (short)0x3F80 : (short)0;
      af[2] = (sA.z == myi) ? (short)0x3F80 : (short)0;
      af[3] = (sA.w == myi) ? (short)0x3F80 : (short)0;
      af[4] = (sB.x == myi) ? (short)0x3F80 : (short)0;
      af[5] = (sB.y == myi) ? (short)0x3F80 : (short)0;
      af[6] = (sB.z == myi) ? (short)0x3F80 : (short)0;
      af[7] = (sB.w == myi) ? (short)0x3F80 : (short)0;
#pragma unroll
      for (int tc = 0; tc < 4; ++tc) {
        const int c = tc * 16 + mrow;
        const bf16x8 bx = *reinterpret_cast<const bf16x8*>(ldsx + c * ROWB + k0 * 2);
        const bf16x8 bq = *reinterpret_cast<const bf16x8*>(ldsq + c * ROWB + k0 * 2);
        accs[tc] = __builtin_amdgcn_mfma_f32_16x16x32_bf16(af, bx, accs[tc], 0, 0, 0);
        accq[tc] = __builtin_amdgcn_mfma_f32_16x16x32_bf16(af, bq, accq[tc], 0, 0, 0);
      }
    }
    __syncthreads();
  }
  if (mode) {
    float* myp = part + (size_t)blockIdx.x * (2 * NI * CH);
#pragma unroll
    for (int tc = 0; tc < 4; ++tc)
#pragma unroll
      for (int r = 0; r < 4; ++r) {
        const int i = i_base + kgrp * 4 + r;
        const int c = tc * 16 + mrow;
        myp[i * CH + c] = accs[tc][r];
        myp[NI * CH + i * CH + c] = accq[tc][r];
      }
  } else {
#pragma unroll
    for (int tc = 0; tc < 4; ++tc)
#pragma unroll
      for (int r = 0; r < 4; ++r) {
        const int i = i_base + kgrp * 4 + r;
        const int c = tc * 16 + mrow;
        atomicAdd(&g_s[i * CH + c], accs[tc][r]);
        atomicAdd(&g_s2[i * CH + c], accq[tc][r]);
      }
  }
}

// ---- parallel partial reducer: slices over block-dim + atomic flush ----
// dst MUST be zero-initialized. grid = (len/256) * NSL.
__global__ __launch_bounds__(256) void k_reduce2(const float* __restrict__ part,
                                                 float* __restrict__ dst,
                                                 int nblk, int len) {
  const int ecols = len >> 8;
  const int sl = blockIdx.x / ecols;
  const int eb = blockIdx.x - sl * ecols;
  const int e = eb * 256 + threadIdx.x;
  const int per = nblk / NSL;
  const int b0 = sl * per;
  const int b1 = (sl == NSL - 1) ? nblk : b0 + per;
  float acc = 0.f;
  for (int b = b0; b < b1; ++b) acc += part[(size_t)b * len + e];
  atomicAdd(&dst[e], acc);
}

// ---- K2: inv = rsqrt(var+eps), mi = mu*inv (proven) ----
__global__ __launch_bounds__(256) void k_musig(const float* __restrict__ g_s,
                                               const float* __restrict__ g_s2,
                                               const unsigned* __restrict__ cnt,
                                               float* __restrict__ g_inv,
                                               float* __restrict__ g_mi) {
  const int i = blockIdx.x * 256 + threadIdx.x;
  const float c = fmaxf((float)cnt[i >> 6], 1.f);
  const float mu = g_s[i] / c;
  const float var = fmaxf(g_s2[i] / c - mu * mu, 0.f);
  const float inv = rsqrtf(var + EPSV);
  g_inv[i] = inv;
  g_mi[i] = mu * inv;
}

// ---- K3: streaming relu-segsum via one-hot MFMA (proven r9) ----
__global__ __launch_bounds__(256) void k_mrsum(const float* __restrict__ f,
                                               const int* __restrict__ seg,
                                               const float* __restrict__ g_inv,
                                               const float* __restrict__ g_mi,
                                               float* __restrict__ part,   // [GRID_M][4096]
                                               float* __restrict__ g_rsum,
                                               int mode, int n, int nchunk) {
  __shared__ __align__(16) int stash[CHUNKP];
  __shared__ __align__(16) unsigned char ldsr[CH * ROWB];
  const int t = threadIdx.x;
  const int lane = t & 63, wv = t >> 6;
  const int ptpair = t >> 3;
  const int ch8 = (t & 7) * 8;
  const int i_base = wv * 16;
  const int mrow = lane & 15;
  const int kgrp = lane >> 4;
  const float4* giv = reinterpret_cast<const float4*>(g_inv);
  const float4* gmi = reinterpret_cast<const float4*>(g_mi);
  const int cq = ch8 >> 2;

  f32x4 acc[4] = {{0.f,0.f,0.f,0.f},{0.f,0.f,0.f,0.f},{0.f,0.f,0.f,0.f},{0.f,0.f,0.f,0.f}};

  for (int ck = blockIdx.x; ck < nchunk; ck += GRID_M) {
    const int base = ck * CHUNKP;
    if (t < CHUNKP) stash[t] = (base + t < n) ? seg[base + t] : -1;
    __syncthreads();
    {
      const int r0 = base + 2 * ptpair;
      const float m0 = (r0 < n) ? 1.f : 0.f;
      const float m1 = (r0 + 1 < n) ? 1.f : 0.f;
      float va[8], vb[8];
      if (r0 < n) {
        *reinterpret_cast<float4*>(&va[0]) = *reinterpret_cast<const float4*>(f + (size_t)r0 * CH + ch8);
        *reinterpret_cast<float4*>(&va[4]) = *reinterpret_cast<const float4*>(f + (size_t)r0 * CH + ch8 + 4);
      } else {
#pragma unroll
        for (int j = 0; j < 8; ++j) va[j] = 0.f;
      }
      if (r0 + 1 < n) {
        *reinterpret_cast<float4*>(&vb[0]) = *reinterpret_cast<const float4*>(f + (size_t)(r0 + 1) * CH + ch8);
        *reinterpret_cast<float4*>(&vb[4]) = *reinterpret_cast<const float4*>(f + (size_t)(r0 + 1) * CH + ch8 + 4);
      } else {
#pragma unroll
        for (int j = 0; j < 8; ++j) vb[j] = 0.f;
      }
      int ins0 = stash[2 * ptpair];     if (ins0 < 0) ins0 = 0;
      int ins1 = stash[2 * ptpair + 1]; if (ins1 < 0) ins1 = 0;
      float iva[8], mia[8], ivb[8], mib[8];
      *reinterpret_cast<float4*>(&iva[0]) = giv[ins0 * 16 + cq];
      *reinterpret_cast<float4*>(&iva[4]) = giv[ins0 * 16 + cq + 1];
      *reinterpret_cast<float4*>(&mia[0]) = gmi[ins0 * 16 + cq];
      *reinterpret_cast<float4*>(&mia[4]) = gmi[ins0 * 16 + cq + 1];
      *reinterpret_cast<float4*>(&ivb[0]) = giv[ins1 * 16 + cq];
      *reinterpret_cast<float4*>(&ivb[4]) = giv[ins1 * 16 + cq + 1];
      *reinterpret_cast<float4*>(&mib[0]) = gmi[ins1 * 16 + cq];
      *reinterpret_cast<float4*>(&mib[4]) = gmi[ins1 * 16 + cq + 1];
#pragma unroll
      for (int j = 0; j < 8; ++j) {
        const int c = ch8 + j;
        const float x0 = fmaxf(fmaf(va[j], iva[j], -mia[j]), 0.f) * m0;
        const float x1 = fmaxf(fmaf(vb[j], ivb[j], -mib[j]), 0.f) * m1;
        *reinterpret_cast<unsigned*>(ldsr + c * ROWB + ptpair * 4) =
            (unsigned)rne_bf16(x0) | ((unsigned)rne_bf16(x1) << 16);
      }
    }
    __syncthreads();
#pragma unroll
    for (int kt = 0; kt < 2; ++kt) {
      const int k0 = kt * 32 + kgrp * 8;
      const int4 sA = *reinterpret_cast<const int4*>(&stash[k0]);
      const int4 sB = *reinterpret_cast<const int4*>(&stash[k0 + 4]);
      const int myi = i_base + mrow;
      bf16x8 af;
      af[0] = (sA.x == myi) ? (short)0x3F80 : (short)0;
      af[1] = (sA.y == myi) ? (short)0x3F80 : (short)0;
      af[2] = (sA.z == myi) ? (short)0x3F80 : (short)0;
      af[3] = (sA.w == myi) ? (short)0x3F80 : (short)0;
      af[4] = (sB.x == myi) ? (short)0x3F80 : (short)0;
      af[5] = (sB.y == myi) ? (short)0x3F80 : (short)0;
      af[6] = (sB.z == myi) ? (short)0x3F80 : (short)0;
      af[7] = (sB.w == myi) ? (short)0x3F80 : (short)0;
#pragma unroll
      for (int tc = 0; tc < 4; ++tc) {
        const int c = tc * 16 + mrow;
        const bf16x8 br = *reinterpret_cast<const bf16x8*>(ldsr + c * ROWB + k0 * 2);
        acc[tc] = __builtin_amdgcn_mfma_f32_16x16x32_bf16(af, br, acc[tc], 0, 0, 0);
      }
    }
    __syncthreads();
  }
  if (mode) {
    float* myp = part + (size_t)blockIdx.x * (NI * CH);
#pragma unroll
    for (int tc = 0; tc < 4; ++tc)
#pragma unroll
      for (int r = 0; r < 4; ++r)
        myp[(i_base + kgrp * 4 + r) * CH + tc * 16 + mrow] = acc[tc][r];
  } else {
#pragma unroll
    for (int tc = 0; tc < 4; ++tc)
#pragma unroll
      for (int r = 0; r < 4; ++r)
        atomicAdd(&g_rsum[(i_base + kgrp * 4 + r) * CH + tc * 16 + mrow], acc[tc][r]);
  }
}

// ---- K4: m = rsum/cnt -> conv3 -> sigmoid -> A,B (proven) ----
__global__ __launch_bounds__(256) void k_eca(const float* __restrict__ g_rsum,
                                             const unsigned* __restrict__ cnt,
                                             const float* __restrict__ ew,
                                             const float* __restrict__ g_inv,
                                             const float* __restrict__ g_mi,
                                             float* __restrict__ g_A,
                                             float* __restrict__ g_B) {
  __shared__ float m[NI * CH];
  const int t = threadIdx.x;
  for (int i = t; i < NI * CH; i += 256)
    m[i] = g_rsum[i] / fmaxf((float)cnt[i >> 6], 1.f);
  __syncthreads();
  const float e0 = ew[0], e1 = ew[1], e2 = ew[2];
  for (int i = t; i < NI * CH; i += 256) {
    const int c = i & 63;
    const float a = c ? m[i - 1] : 0.f;
    const float b = m[i];
    const float d = (c < 63) ? m[i + 1] : 0.f;
    const float conv = e0 * a + e1 * b + e2 * d;
    const float w = 1.f / (1.f + expf(-conv));
    g_A[i] = g_inv[i] * w;
    g_B[i] = g_mi[i] * w;
  }
}

// ---- K5: out = relu(fma(f, A, -B)) streaming (proven @~6.2 TB/s) ----
__global__ __launch_bounds__(256) void k_out(const float* __restrict__ f,
                                             const int* __restrict__ seg,
                                             const float* __restrict__ g_A,
                                             const float* __restrict__ g_B,
                                             float* __restrict__ out, int n) {
  __shared__ float tA[NI * PADT];
  __shared__ float tB[NI * PADT];
  const int t = threadIdx.x;
  for (int i = t; i < NI * CH; i += 256) {
    const int a = (i >> 6) * PADT + (i & 63);
    tA[a] = g_A[i];
    tB[a] = g_B[i];
  }
  __syncthreads();
  const int sub = t & 15, c0 = sub << 2, pib = t >> 4;
  const int pstride = gridDim.x << 4;
  for (int p = (blockIdx.x << 4) + pib; p < n; p += pstride) {
    const float4 v = *reinterpret_cast<const float4*>(f + (size_t)p * CH + c0);
    const int tb = seg[p] * PADT + c0;
    const float4 a = *reinterpret_cast<const float4*>(tA + tb);
    const float4 b = *reinterpret_cast<const float4*>(tB + tb);
    float4 o;
    o.x = fmaxf(fmaf(v.x, a.x, -b.x), 0.f);
    o.y = fmaxf(fmaf(v.y, a.y, -b.y), 0.f);
    o.z = fmaxf(fmaf(v.z, a.z, -b.z), 0.f);
    o.w = fmaxf(fmaf(v.w, a.w, -b.w), 0.f);
    *reinterpret_cast<float4*>(out + (size_t)p * CH + c0) = o;
  }
}

// ================= launch =================
extern "C" void kernel_launch(void* const* d_in, const int* in_sizes, int n_in,
                              void* d_out, int out_size, void* d_ws, size_t ws_size,
                              hipStream_t stream) {
  const float* f   = (const float*)d_in[0];
  const int*   seg = (const int*)d_in[1];
  const float* ew  = (const float*)d_in[2];
  float* out = (float*)d_out;
  const int n = in_sizes[1];
  const int nchunk = (n + CHUNKP - 1) / CHUNKP;

  // ws layout (float offsets)
  float* ws      = (float*)d_ws;
  float* g_s     = ws;                       // 4096
  float* g_s2    = ws + 4096;                // 4096 (contiguous with g_s for combined reduce)
  float* g_rsum  = ws + 8192;                // 4096
  unsigned* hist = (unsigned*)(ws + 12288);  // 64
  float* g_inv   = ws + 12352;               // 4096
  float* g_mi    = ws + 16448;               // 4096
  float* g_A     = ws + 20544;               // 4096
  float* g_B     = ws + 24640;               // 4096
  float* part1   = ws + 28736;               // GRID_M * 8192
  float* part3   = part1 + (size_t)GRID_M * 8192;  // GRID_M * 4096
  const size_t need = (28736 + (size_t)GRID_M * 8192 + (size_t)GRID_M * 4096) * 4;
  const int mode = (ws_size >= need) ? 1 : 0;

  // zero g_s, g_s2, g_rsum, hist (reducer atomics + mode-0 atomics need zeros)
  (void)hipMemsetAsync(d_ws, 0, 12352 * sizeof(float), stream);

  k_hist<<<256, 256, 0, stream>>>(seg, hist, n);
  k_mstats<<<GRID_M, 256, 0, stream>>>(f, seg, part1, g_s, g_s2, mode, n, nchunk);
  if (mode) k_reduce2<<<(8192 / 256) * NSL, 256, 0, stream>>>(part1, g_s /* + g_s2 */, GRID_M, 8192);
  k_musig<<<16, 256, 0, stream>>>(g_s, g_s2, hist, g_inv, g_mi);
  k_mrsum<<<GRID_M, 256, 0, stream>>>(f, seg, g_inv, g_mi, part3, g_rsum, mode, n, nchunk);
  if (mode) k_reduce2<<<(4096 / 256) * NSL, 256, 0, stream>>>(part3, g_rsum, GRID_M, 4096);
  k_eca<<<1, 256, 0, stream>>>(g_rsum, hist, ew, g_inv, g_mi, g_A, g_B);
  k_out<<<2048, 256, 0, stream>>>(f, seg, g_A, g_B, out, n);
}